// Round 9
// baseline (134.059 us; speedup 1.0000x reference)
//
#include <hip/hip_runtime.h>

typedef __bf16 bf16x8 __attribute__((ext_vector_type(8)));
typedef float f32x4 __attribute__((ext_vector_type(4)));
typedef unsigned int u32x4 __attribute__((ext_vector_type(4)));

__device__ __forceinline__ unsigned short f2bf(float f) {
  unsigned u = __builtin_bit_cast(unsigned, f);
  u += 0x7FFFu + ((u >> 16) & 1u);
  return (unsigned short)(u >> 16);
}

// async global->LDS, 16B/lane; LDS dest = wave-uniform base + lane*16 (HW rule)
__device__ __forceinline__ void gl2lds16(const void* g, void* l) {
  __builtin_amdgcn_global_load_lds((const __attribute__((address_space(1))) void*)g,
                                   (__attribute__((address_space(3))) void*)l, 16, 0, 0);
}

__device__ __forceinline__ bf16x8 cvt8v(f32x4 a, f32x4 b) {
  bf16x8 r;
  r[0] = (__bf16)a[0]; r[1] = (__bf16)a[1]; r[2] = (__bf16)a[2]; r[3] = (__bf16)a[3];
  r[4] = (__bf16)b[0]; r[5] = (__bf16)b[1]; r[6] = (__bf16)b[2]; r[7] = (__bf16)b[3];
  return r;
}

// ---------------- W transpose: W[512 f][512 d] f32 -> Wt[512 d][512 f] bf16 --------
__global__ void transpose_cvt(const float* __restrict__ in, unsigned short* __restrict__ out) {
  __shared__ float tile[32][33];
  const int r0 = blockIdx.x * 32, c0 = blockIdx.y * 32;
  const int tx = threadIdx.x, ty = threadIdx.y;
#pragma unroll
  for (int i = 0; i < 4; ++i) tile[ty + i * 8][tx] = in[(size_t)(r0 + ty + i * 8) * 512 + c0 + tx];
  __syncthreads();
#pragma unroll
  for (int i = 0; i < 4; ++i) {
    const int cc = ty + i * 8;
    out[(size_t)(c0 + cc) * 512 + r0 + tx] = f2bf(tile[tx][cc]);
  }
}

// ---------------- TLP-first m97-style GEMM -----------------------------------------
// 128x128 tile, BK=64. 512 thr = 8 waves as (wr 0..3) x (wc 0..1); wave tile 32x64,
// acc[2][4] = 32 VGPR -> launch_bounds(512,4) caps VGPR at 128. Single-buffer 48KB
// frag-ordered LDS (A fp32 32KB | B bf16 16KB) -> grid 512 = 2 blocks/CU =
// 16 waves/CU (2x every prior round). Plain m97 2-barrier loop: stage -> sync ->
// compute -> sync; the co-resident anti-phased block covers the barrier drain
// (m114 cross-block overlap). Frag-ordered LDS: lane L's 16B at fragbase + L*16 ->
// stride-1, zero bank conflicts; staging via per-lane pre-permuted global source.
template <int APITCH, int BPITCH, int NT, bool IS_Y>
__global__ __launch_bounds__(512, 4) void gemm_tlp(const float* __restrict__ A0,
                                                   const unsigned short* __restrict__ B0,
                                                   unsigned short* __restrict__ yT,
                                                   int* __restrict__ mask,
                                                   float* __restrict__ out) {
  __shared__ __align__(16) char lds[49152];  // A 32KB | B 16KB

  const int bid = blockIdx.x;
  int b, m0, n0;
  const float* Ab;
  const unsigned short* Bb;
  if constexpr (IS_Y) {
    const int mt = bid >> 2, nt = bid & 3;  // 128 m-tiles (M_flat=16384) x 4 n-tiles
    b = mt >> 4; m0 = (mt & 15) * 128; n0 = nt * 128;
    Ab = A0 + ((size_t)b * 2048 + m0) * APITCH;
    Bb = B0 + (size_t)n0 * BPITCH;
  } else {
    b = bid & 7;  // batch -> XCD pin (yT[b] L2 locality)
    const int idx = bid >> 3;
    m0 = (idx & 15) * 128; n0 = (idx >> 4) * 128;
    Ab = A0 + ((size_t)b * 2048 + m0) * APITCH;
    Bb = B0 + ((size_t)b * 512 + n0) * BPITCH;
  }

  const int tid = threadIdx.x, w = tid >> 6, L = tid & 63;
  const int wr = w >> 1, wc = w & 1, r = L & 15, hi = L >> 4;
  const int Lof = L * 16;

  // staging sources: wave w owns row-group rg=w (A rows w*16+r) and col-group
  // cg=w (B rows w*16+r). Per iter: A 4 insts (kk{0,1} x lo/hh), B 2 (kk{0,1}).
  const char* aSrc = (const char*)Ab + ((size_t)(w * 16 + r) * APITCH + hi * 8) * 4;
  const char* bSrc = (const char*)Bb + ((size_t)(w * 16 + r) * BPITCH + hi * 8) * 2;

  f32x4 acc[2][4] = {};
  unsigned anz[2] = {0u, 0u};

#pragma unroll 1
  for (int t = 0; t < NT; ++t) {
    // ---- stage tile t (6 x global_load_lds per wave) ----
    {
      const char* as = aSrc + (size_t)t * 256;  // BK=64 fp32 = 256B
      const char* bs = bSrc + (size_t)t * 128;  // BK=64 bf16 = 128B
      char* af = lds + (w * 2) * 2048;          // A frag f = w*2 + kk, 2KB each
      gl2lds16(as, af);                          // kk0 lo
      gl2lds16(as + 16, af + 1024);              // kk0 hh
      gl2lds16(as + 128, af + 2048);             // kk1 lo
      gl2lds16(as + 144, af + 3072);             // kk1 hh
      char* bf = lds + 32768 + (w * 2) * 1024;   // B frag g = w*2 + kk, 1KB each
      gl2lds16(bs, bf);
      gl2lds16(bs + 64, bf + 1024);
    }
    __syncthreads();  // compiler drains vmcnt; co-resident block computes meanwhile

    // ---- compute tile t ----
#pragma unroll
    for (int kk = 0; kk < 2; ++kk) {
      bf16x8 bfr[4];
#pragma unroll
      for (int ni = 0; ni < 4; ++ni)
        bfr[ni] = *(const bf16x8*)(lds + 32768 + (((wc * 4 + ni) * 2 + kk) << 10) + Lof);
#pragma unroll
      for (int mi = 0; mi < 2; ++mi) {
        const char* fb = lds + (((wr * 2 + mi) * 2 + kk) << 11);
        f32x4 lo = *(const f32x4*)(fb + Lof);
        f32x4 hh = *(const f32x4*)(fb + 1024 + Lof);
        if constexpr (IS_Y) {
          if (wc == 0) {  // exact row mask from raw fp32 bits (pre-cvt)
            u32x4 u0 = __builtin_bit_cast(u32x4, lo), u1 = __builtin_bit_cast(u32x4, hh);
            anz[mi] |= (u0[0] | u0[1] | u0[2] | u0[3] | u1[0] | u1[1] | u1[2] | u1[3]) &
                       0x7fffffffu;
          }
        }
        bf16x8 af = cvt8v(lo, hh);
#pragma unroll
        for (int ni = 0; ni < 4; ++ni)
          acc[mi][ni] =
              __builtin_amdgcn_mfma_f32_16x16x32_bf16(af, bfr[ni], acc[mi][ni], 0, 0, 0);
      }
    }
    if (t + 1 < NT) __syncthreads();  // readers done before next stage overwrites
  }

  if constexpr (IS_Y) {
    if (wc == 0) {
#pragma unroll
      for (int mi = 0; mi < 2; ++mi) {
        unsigned v = anz[mi];
        v |= __shfl_xor(v, 16);
        v |= __shfl_xor(v, 32);
        if (hi == 0) mask[b * 2048 + m0 + (wr * 2 + mi) * 16 + r] = (v != 0u) ? 1 : 0;
      }
    }
    // yT[b][d][n] store: rr runs along n -> contiguous 8B stores
#pragma unroll
    for (int mi = 0; mi < 2; ++mi)
#pragma unroll
      for (int ni = 0; ni < 4; ++ni) {
        const int col = n0 + wc * 64 + ni * 16 + r;
        const int nrow = m0 + wr * 32 + mi * 16 + hi * 4;
        ushort4 s;
        s.x = f2bf(acc[mi][ni][0]);
        s.y = f2bf(acc[mi][ni][1]);
        s.z = f2bf(acc[mi][ni][2]);
        s.w = f2bf(acc[mi][ni][3]);
        *(ushort4*)(yT + (((size_t)b * 512 + col) << 11) + nrow) = s;
      }
  } else {
    const int* mrow = mask + b * 2048 + m0 + wr * 32;
#pragma unroll
    for (int mi = 0; mi < 2; ++mi) {
      const int4 mv = *(const int4*)(mrow + mi * 16 + hi * 4);
      const int mvv[4] = {mv.x, mv.y, mv.z, mv.w};
#pragma unroll
      for (int ni = 0; ni < 4; ++ni) {
        const int col = n0 + wc * 64 + ni * 16 + r;
        float* op = out + (size_t)(b * 2048 + m0 + wr * 32 + mi * 16 + hi * 4) * 512 + col;
#pragma unroll
        for (int rr = 0; rr < 4; ++rr) {
          float v = fmaxf(acc[mi][ni][rr], 0.0f);
          if (mvv[rr] == 0) v = 0.0f;
          op[(size_t)rr * 512] = v;
        }
      }
    }
  }
}

// ---------------- launch ----------------------------------------------------------
extern "C" void kernel_launch(void* const* d_in, const int* in_sizes, int n_in,
                              void* d_out, int out_size, void* d_ws, size_t ws_size,
                              hipStream_t stream) {
  const float* x = (const float*)d_in[0];   // [8][2048][512]
  const float* a = (const float*)d_in[1];   // [8][2048][2048]
  const float* wk = (const float*)d_in[2];  // [512][512]
  float* out = (float*)d_out;               // [8][2048][512]

  char* ws = (char*)d_ws;
  unsigned short* wT = (unsigned short*)ws;                 // 512 KB
  unsigned short* yT = (unsigned short*)(ws + (1u << 19));  // 16 MB
  int* mask = (int*)(ws + (1u << 19) + (16u << 20));        // 64 KB

  transpose_cvt<<<dim3(16, 16), dim3(32, 8), 0, stream>>>(wk, wT);
  // y^T = (x @ W)^T (bf16) + exact row mask.  M_flat=16384, N=512, K=512.
  gemm_tlp<512, 512, 8, true><<<512, 512, 0, stream>>>(x, wT, yT, mask, nullptr);
  // out = relu(a @ y) * mask.  Per batch M=2048, N=512 (d), K=2048 (n).
  gemm_tlp<2048, 2048, 32, false><<<512, 512, 0, stream>>>(a, yT, nullptr, mask, out);
}